// Round 13
// baseline (664.211 us; speedup 1.0000x reference)
//
#include <hip/hip_runtime.h>
#include <stdint.h>

#define D_MODEL 1024
#define D_FF    4096
#define NHEADS  16
#define HD      64
#define LN_EPS  1e-5f

using u16 = unsigned short;
typedef __bf16 bf16x8 __attribute__((ext_vector_type(8)));
typedef float  f32x4  __attribute__((ext_vector_type(4)));
typedef float  f32x16 __attribute__((ext_vector_type(16)));

typedef __attribute__((address_space(1))) uint32_t as1_u32;
typedef __attribute__((address_space(3))) uint32_t as3_u32;

__device__ __forceinline__ u16 f2bf(float f) {
  union { float f; uint32_t u; } v; v.f = f;
  uint32_t r = v.u + 0x7FFFu + ((v.u >> 16) & 1u);
  return (u16)(r >> 16);
}

__device__ __forceinline__ float bf2f(u16 u) {
  union { uint32_t u; float f; } v; v.u = (uint32_t)u << 16; return v.f;
}

__device__ __forceinline__ uint32_t cvtpk(float lo, float hi) {
  uint32_t r;
  asm("v_cvt_pk_bf16_f32 %0, %1, %2" : "=v"(r) : "v"(lo), "v"(hi));
  return r;
}

__device__ __forceinline__ void gl_lds16(const void* g, void* l) {
  __builtin_amdgcn_global_load_lds((const as1_u32*)(uintptr_t)g,
                                   (as3_u32*)(uint32_t)(uintptr_t)l, 16, 0, 0);
}

// ---------------- transpose + cast: W (K x N, f32) -> Wt (N x K, bf16) ----------------
__global__ __launch_bounds__(256)
void transpose_cast(const float* __restrict__ W, u16* __restrict__ Wt, int K, int N) {
  __shared__ float t[32][33];
  const int k0 = blockIdx.x * 32, n0 = blockIdx.y * 32;
  const int x = threadIdx.x & 31, y = threadIdx.x >> 5;
#pragma unroll
  for (int j = 0; j < 32; j += 8)
    t[y + j][x] = W[(size_t)(k0 + y + j) * N + (n0 + x)];
  __syncthreads();
#pragma unroll
  for (int j = 0; j < 32; j += 8)
    Wt[(size_t)(n0 + y + j) * K + (k0 + x)] = f2bf(t[x][y + j]);
}

// 8 square (1024x1024) weight transposes in one dispatch; dst slabs contiguous.
struct Src8 { const float* s[8]; };
__global__ __launch_bounds__(256)
void transpose_cast8(Src8 p, u16* __restrict__ dstbase) {
  __shared__ float t[32][33];
  const float* __restrict__ W = p.s[blockIdx.z];
  u16* __restrict__ Wt = dstbase + (size_t)blockIdx.z * (1024 * 1024);
  const int k0 = blockIdx.x * 32, n0 = blockIdx.y * 32;
  const int x = threadIdx.x & 31, y = threadIdx.x >> 5;
#pragma unroll
  for (int j = 0; j < 32; j += 8)
    t[y + j][x] = W[(size_t)(k0 + y + j) * 1024 + (n0 + x)];
  __syncthreads();
#pragma unroll
  for (int j = 0; j < 32; j += 8)
    Wt[(size_t)(n0 + y + j) * 1024 + (k0 + x)] = f2bf(t[x][y + j]);
}

// ---------------- elementwise cast f32 -> bf16 ----------------
__global__ __launch_bounds__(256)
void cast_f32_bf16(const float* __restrict__ in, u16* __restrict__ out, int n4) {
  int i = blockIdx.x * 256 + threadIdx.x;
  if (i < n4) {
    float4 v = ((const float4*)in)[i];
    ushort4 o;
    o.x = f2bf(v.x); o.y = f2bf(v.y); o.z = f2bf(v.z); o.w = f2bf(v.w);
    ((ushort4*)out)[i] = o;
  }
}

// ---------------- LayerNorm (f32 or bf16 in, bf16 out), block per row ----------------
template<int BF16IN>
__global__ __launch_bounds__(256)
void ln_bf16(const float* __restrict__ xf, const u16* __restrict__ xb,
             const float* __restrict__ g, const float* __restrict__ bta,
             u16* __restrict__ out) {
  const int row = blockIdx.x;
  const int tid = threadIdx.x;
  float4 v;
  if (BF16IN) {
    ushort4 u = ((const ushort4*)(xb + (size_t)row * D_MODEL))[tid];
    v.x = bf2f(u.x); v.y = bf2f(u.y); v.z = bf2f(u.z); v.w = bf2f(u.w);
  } else {
    v = ((const float4*)(xf + (size_t)row * D_MODEL))[tid];
  }
  float s  = v.x + v.y + v.z + v.w;
  float s2 = v.x * v.x + v.y * v.y + v.z * v.z + v.w * v.w;
#pragma unroll
  for (int off = 1; off < 64; off <<= 1) {
    s  += __shfl_xor(s, off);
    s2 += __shfl_xor(s2, off);
  }
  __shared__ float sm[8];
  const int wave = tid >> 6, lane = tid & 63;
  if (lane == 0) { sm[wave] = s; sm[4 + wave] = s2; }
  __syncthreads();
  s  = sm[0] + sm[1] + sm[2] + sm[3];
  s2 = sm[4] + sm[5] + sm[6] + sm[7];
  const float mean = s * (1.f / D_MODEL);
  const float var  = s2 * (1.f / D_MODEL) - mean * mean;
  const float rstd = rsqrtf(var + LN_EPS);
  const float4 gv = ((const float4*)g)[tid];
  const float4 bv = ((const float4*)bta)[tid];
  ushort4 o;
  o.x = f2bf((v.x - mean) * rstd * gv.x + bv.x);
  o.y = f2bf((v.y - mean) * rstd * gv.y + bv.y);
  o.z = f2bf((v.z - mean) * rstd * gv.z + bv.z);
  o.w = f2bf((v.w - mean) * rstd * gv.w + bv.w);
  ((ushort4*)(out + (size_t)row * D_MODEL))[tid] = o;
}

// ---------------- GEMM: C[M,N] = A[M,K](bf16) * Wt[N,K]^T(bf16) + bias ----------------
// 1-D grid with XCD-bijective swizzle (nwg % 8 == 0), decoded M-tile-fastest so
// each XCD owns whole 128-col B-panels (L2-resident).
// EPI 0: bf16   EPI 1: relu->bf16
// EPI 2: bf16 = acc+bias+residf(f32)     EPI 3: bf16 * 0.125*log2e (Q proj)
// EPI 4: merged QKV -> q dense (scaled), k dense, V -> V^T [b][h][d][t]
// EPI 5: merged KV  -> k dense, V -> V^T
// EPI 6: bf16 = acc+bias+residb(bf16)    EPI 7: f32 = acc+bias+residb(bf16)
#define QSCALE 0.18033688011112042f
template<int EPI>
__global__ __launch_bounds__(256, 3)
void gemm_bf16(const u16* __restrict__ A, const u16* __restrict__ Wt,
               const float* __restrict__ bias, const float* __restrict__ bias2,
               const float* __restrict__ bias3,
               const float* __restrict__ residf, const u16* __restrict__ residb,
               u16* __restrict__ outb, u16* __restrict__ outb2, u16* __restrict__ outb3,
               float* outf, int M, int N, int K) {
  __shared__ u16 lA[128 * 32];
  __shared__ u16 lB[128 * 32];
  const int tid  = threadIdx.x;
  const int lane = tid & 63;
  const int wave = tid >> 6;
  const int wr = wave >> 1, wc = wave & 1;
  const int lr = lane & 15, lg = lane >> 4;

  // XCD swizzle: hw block b (b%8 = XCD) -> logical wg, XCD k covers contiguous chunk
  const int cpx = gridDim.x >> 3;
  const int wg  = (blockIdx.x & 7) * cpx + (blockIdx.x >> 3);
  const int gx  = M >> 7;
  const int row0 = (wg % gx) << 7;
  const int col0 = (wg / gx) << 7;

  const char* pa = (const char*)A  + ((size_t)(row0 + (tid >> 2)) * K + (size_t)(tid & 3) * 8) * 2;
  const char* pb = (const char*)Wt + ((size_t)(col0 + (tid >> 2)) * K + (size_t)(tid & 3) * 8) * 2;
  const size_t rowskip = (size_t)64 * K * 2;
  char* la = (char*)lA + wave * 1024;
  char* lb = (char*)lB + wave * 1024;

  f32x4 acc[4][4] = {};
  const int ksteps = K >> 5;
  for (int kt = 0; kt < ksteps; ++kt) {
    gl_lds16(pa, la);
    gl_lds16(pa + rowskip, la + 4096);
    gl_lds16(pb, lb);
    gl_lds16(pb + rowskip, lb + 4096);
    pa += 64; pb += 64;
    __syncthreads();
    bf16x8 af[4], bfr[4];
#pragma unroll
    for (int m = 0; m < 4; ++m)
      af[m] = *(const bf16x8*)((const char*)lA + (wr * 64 + m * 16 + lr) * 64 + lg * 16);
#pragma unroll
    for (int n = 0; n < 4; ++n)
      bfr[n] = *(const bf16x8*)((const char*)lB + (wc * 64 + n * 16 + lr) * 64 + lg * 16);
#pragma unroll
    for (int m = 0; m < 4; ++m)
#pragma unroll
      for (int n = 0; n < 4; ++n)
        acc[m][n] = __builtin_amdgcn_mfma_f32_16x16x32_bf16(af[m], bfr[n], acc[m][n], 0, 0, 0);
    __syncthreads();
  }

#pragma unroll
  for (int m = 0; m < 4; ++m) {
    const int grow = row0 + wr * 64 + m * 16 + lg * 4;
#pragma unroll
    for (int n = 0; n < 4; ++n) {
      const int gcol = col0 + wc * 64 + n * 16 + lr;
      if (EPI == 4 || EPI == 5) {
        const int seg = gcol >> 10;
        const int c = gcol & 1023;
        const bool isV = (EPI == 4) ? (seg == 2) : (seg == 1);
        if (isV) {
          // V^T layout: [b][h][d][t], t = 4 consecutive rows -> one 8B store
          const float bv = (EPI == 4 ? bias3 : bias2)[c];
          const int hh = c >> 6, dd = c & 63;
          const int bb = grow >> 11, tt = grow & 2047;
          u16* vT = (EPI == 4) ? outb3 : outb2;
          uint2 st;
          st.x = cvtpk(acc[m][n][0] + bv, acc[m][n][1] + bv);
          st.y = cvtpk(acc[m][n][2] + bv, acc[m][n][3] + bv);
          *(uint2*)(vT + (((size_t)(bb * NHEADS + hh) * 64 + dd) << 11) + tt) = st;
        } else {
          const float bv = ((EPI == 4) ? ((seg == 0) ? bias : bias2) : bias)[c];
          const float sc = (EPI == 4 && seg == 0) ? QSCALE : 1.f;
          u16* optr = (EPI == 4) ? ((seg == 0) ? outb : outb2) : outb;
#pragma unroll
          for (int r = 0; r < 4; ++r)
            optr[(size_t)(grow + r) * 1024 + c] = f2bf((acc[m][n][r] + bv) * sc);
        }
      } else {
        const float bv = bias[gcol];
#pragma unroll
        for (int r = 0; r < 4; ++r) {
          const size_t idx = (size_t)(grow + r) * N + gcol;
          float v = acc[m][n][r] + bv;
          if (EPI == 0)      outb[idx] = f2bf(v);
          else if (EPI == 1) outb[idx] = f2bf(v > 0.f ? v : 0.f);
          else if (EPI == 2) outb[idx] = f2bf(v + residf[idx]);
          else if (EPI == 3) outb[idx] = f2bf(v * QSCALE);
          else if (EPI == 6) outb[idx] = f2bf(v + bf2f(residb[idx]));
          else               outf[idx] = v + bf2f(residb[idx]);   // EPI 7
        }
      }
    }
  }
}

// ---------------- Flash attention, swapped-operand 32x32 form (r12-verified) ----------------
// 128 q-rows/block (4 waves x 32), 64-wide KV tiles. S^T = mfma(K,Q): lane owns
// one q-row. K staged with sigma = swap bits 2<->3 so P fragments are direct
// register packs. V arrives pre-transposed ([b][h][d][t]); V^T swizzle key
// (d>>3)&7 flips bit 2 between 32-row chunks -> chunk 1 source granule sgv^4.
template<bool CAUSAL>
__global__ __launch_bounds__(256, 4)
void attn_kernel(const u16* __restrict__ Q, const u16* __restrict__ Kb,
                 const u16* __restrict__ Vt, u16* __restrict__ O,
                 int T, int S) {
  __shared__ u16 lQ[128 * 64];
  __shared__ u16 lK[64 * 64];
  __shared__ u16 lVt[64 * 64];

  const int f  = blockIdx.x;
  const int bh = f & 63;
  const int b = bh >> 4, hd = bh & 15;
  const int qx = f >> 6;
  const int q0 = (CAUSAL ? (T / 128 - 1 - qx) : qx) * 128;
  const int tid = threadIdx.x, lane = tid & 63, wave = tid >> 6;
  const int l31 = lane & 31, hb = lane >> 5;

  const u16* Qbase = Q  + (size_t)(b * T) * D_MODEL + hd * HD;
  const u16* Kbase = Kb + (size_t)(b * S) * D_MODEL + hd * HD;
  const u16* Vbase = Vt + ((size_t)(b * NHEADS + hd) << 17);   // [64][2048] u16
  const size_t rskip = (size_t)32 * D_MODEL * 2;

  const int srow = tid >> 3;
  const int sg   = (tid & 7) ^ (srow & 7);
  const int sgv0 = (tid & 7) ^ ((srow >> 3) & 7);   // chunk 0: d = srow
  const int sgv1 = sgv0 ^ 4;                        // chunk 1: d = srow+32
  const int sprow = (srow & ~12) | ((srow & 4) << 1) | ((srow & 8) >> 1);

  // stage Q: 128 rows x 128B (pre-swizzled source)
  {
    const char* src = (const char*)(Qbase + (size_t)(q0 + srow) * D_MODEL) + sg * 16;
    char* dst = (char*)lQ + wave * 1024;
    gl_lds16(src,             dst);
    gl_lds16(src + rskip,     dst + 4096);
    gl_lds16(src + 2 * rskip, dst + 8192);
    gl_lds16(src + 3 * rskip, dst + 12288);
  }

  bf16x8 qf[4];
  f32x16 oacc0 = {}, oacc1 = {};
  float m_run = -1e30f, l_run = 0.f;
  const int qq = q0 + wave * 32 + l31;

  const int ktEnd = CAUSAL ? (q0 / 64 + 2) : (S / 64);

  for (int kt = 0; kt < ktEnd; ++kt) {
    {
      const char* src = (const char*)(Kbase + (size_t)(kt * 64 + sprow) * D_MODEL) + sg * 16;
      char* dst = (char*)lK + wave * 1024;
      gl_lds16(src, dst);
      gl_lds16(src + rskip, dst + 4096);
    }
    {
      const char* srcv = (const char*)(Vbase + ((size_t)srow << 11) + kt * 64);
      char* dst = (char*)lVt + wave * 1024;
      gl_lds16(srcv + sgv0 * 16, dst);
      gl_lds16(srcv + (32u << 12) + sgv1 * 16, dst + 4096);
    }
    __syncthreads();

    if (kt == 0) {
      const int qrow = wave * 32 + l31;
#pragma unroll
      for (int dc = 0; dc < 4; ++dc)
        qf[dc] = *(const bf16x8*)((const char*)lQ + qrow * 128 +
                                  (((2 * dc + hb) ^ (qrow & 7)) << 4));
    }

    const bool live = !CAUSAL || (kt * 64 <= q0 + wave * 32 + 31);
    if (live) {
      f32x16 z0 = {}, z1 = {};
      __builtin_amdgcn_s_setprio(1);
#pragma unroll
      for (int dc = 0; dc < 4; ++dc) {
        bf16x8 kf0 = *(const bf16x8*)((const char*)lK + l31 * 128 +
                                      (((2 * dc + hb) ^ (l31 & 7)) << 4));
        z0 = __builtin_amdgcn_mfma_f32_32x32x16_bf16(kf0, qf[dc], z0, 0, 0, 0);
      }
#pragma unroll
      for (int dc = 0; dc < 4; ++dc) {
        bf16x8 kf1 = *(const bf16x8*)((const char*)lK + (32 + l31) * 128 +
                                      (((2 * dc + hb) ^ (l31 & 7)) << 4));
        z1 = __builtin_amdgcn_mfma_f32_32x32x16_bf16(kf1, qf[dc], z1, 0, 0, 0);
      }
      __builtin_amdgcn_s_setprio(0);

      // causal mask: reg r holds kv = kt*64 + (r&7) + 8*hb + 16*(r>>3)
      if (CAUSAL && kt * 64 + 63 > q0 + wave * 32) {
        const int kvb = kt * 64 + 8 * hb;
#pragma unroll
        for (int r = 0; r < 16; ++r) {
          const int kv = kvb + (r & 7) + 16 * (r >> 3);
          if (kv > qq)      z0[r] = -1e30f;
          if (kv + 32 > qq) z1[r] = -1e30f;
        }
      }

      float t[16];
#pragma unroll
      for (int r = 0; r < 16; ++r) t[r] = fmaxf(z0[r], z1[r]);
#pragma unroll
      for (int sdt = 8; sdt >= 1; sdt >>= 1)
#pragma unroll
        for (int i = 0; i < 8; ++i)
          if (i < sdt) t[i] = fmaxf(t[i], t[i + sdt]);
      float mx = t[0];
      mx = fmaxf(mx, __shfl_xor(mx, 32));

      if (!__all(mx - m_run <= 11.5f)) {
        const float mn = fmaxf(m_run, mx);
        const float scl = exp2f(m_run - mn);
        m_run = mn;
        l_run *= scl;
#pragma unroll
        for (int r = 0; r < 16; ++r) { oacc0[r] *= scl; oacc1[r] *= scl; }
      }
      float sum = 0.f;
#pragma unroll
      for (int r = 0; r < 16; ++r) {
        z0[r] = exp2f(z0[r] - m_run); sum += z0[r];
        z1[r] = exp2f(z1[r] - m_run); sum += z1[r];
      }
      sum += __shfl_xor(sum, 32);
      l_run += sum;

      // pf[c] = regs [8c..8c+7] (elem j -> kv = 16c + 8*hb + j)
      bf16x8 pf[4];
      {
        union { uint32_t u[4]; bf16x8 v; } w0, w1, w2, w3;
#pragma unroll
        for (int i = 0; i < 4; ++i) {
          w0.u[i] = cvtpk(z0[2 * i],     z0[2 * i + 1]);
          w1.u[i] = cvtpk(z0[8 + 2 * i], z0[9 + 2 * i]);
          w2.u[i] = cvtpk(z1[2 * i],     z1[2 * i + 1]);
          w3.u[i] = cvtpk(z1[8 + 2 * i], z1[9 + 2 * i]);
        }
        pf[0] = w0.v; pf[1] = w1.v; pf[2] = w2.v; pf[3] = w3.v;
      }

      __builtin_amdgcn_s_setprio(1);
#pragma unroll
      for (int c = 0; c < 4; ++c) {
        bf16x8 vf0 = *(const bf16x8*)((const char*)lVt + l31 * 128 +
                       (((2 * c + hb) ^ ((l31 >> 3) & 7)) << 4));
        oacc0 = __builtin_amdgcn_mfma_f32_32x32x16_bf16(vf0, pf[c], oacc0, 0, 0, 0);
        bf16x8 vf1 = *(const bf16x8*)((const char*)lVt + (32 + l31) * 128 +
                       ((((2 * c + hb) ^ (((32 + l31) >> 3) & 7))) << 4));
        oacc1 = __builtin_amdgcn_mfma_f32_32x32x16_bf16(vf1, pf[c], oacc1, 0, 0, 0);
      }
      __builtin_amdgcn_s_setprio(0);
    }
    __syncthreads();
  }

  const float linv = 1.f / l_run;
  u16* Op = O + (size_t)(b * T + qq) * D_MODEL + hd * HD + 4 * hb;
#pragma unroll
  for (int rr = 0; rr < 4; ++rr) {
    uint2 st0, st1;
    st0.x = cvtpk(oacc0[4 * rr + 0] * linv, oacc0[4 * rr + 1] * linv);
    st0.y = cvtpk(oacc0[4 * rr + 2] * linv, oacc0[4 * rr + 3] * linv);
    *(uint2*)(Op + 8 * rr) = st0;
    st1.x = cvtpk(oacc1[4 * rr + 0] * linv, oacc1[4 * rr + 1] * linv);
    st1.y = cvtpk(oacc1[4 * rr + 2] * linv, oacc1[4 * rr + 3] * linv);
    *(uint2*)(Op + 32 + 8 * rr) = st1;
  }
}

// ---------------- host ----------------
extern "C" void kernel_launch(void* const* d_in, const int* in_sizes, int n_in,
                              void* d_out, int out_size, void* d_ws, size_t ws_size,
                              hipStream_t stream) {
  (void)in_sizes; (void)n_in; (void)out_size; (void)ws_size;
  const int B = 4, T = 2048, S = 2048, Dm = 1024, F = 4096;
  const int M = B * T;

  const float* x   = (const float*)d_in[0];
  const float* enc = (const float*)d_in[1];

  char* p = (char*)d_ws;
  auto take = [&](size_t bytes) { char* r = p; p += (bytes + 255) & ~(size_t)255; return r; };
  // [0]=sa_qw [1]=sa_kw [2]=sa_vw [3]=sa_ow [4]=ca_qw [5]=ca_kw [6]=ca_vw [7]=ca_ow
  u16* wt8  = (u16*)take((size_t)8 * Dm * Dm * 2);
  u16* ff1T = (u16*)take((size_t)F * Dm * 2);
  u16* ff2T = (u16*)take((size_t)Dm * F * 2);
  u16*   h    = (u16*)take((size_t)M * Dm * 2);
  u16*   encb = (u16*)take((size_t)M * Dm * 2);
  u16*   xc   = (u16*)take((size_t)M * Dm * 2);   // bf16 residual stream
  u16*   xc2  = (u16*)take((size_t)M * Dm * 2);
  char*  Dreg = take((size_t)M * F * 2);            // 64MB reusable region
  u16* qb = (u16*)Dreg;                             // M x 1024 dense
  u16* kb = (u16*)(Dreg + (size_t)M * Dm * 2);
  u16* vb = (u16*)(Dreg + (size_t)2 * M * Dm * 2);  // V^T: [B][H][64][T]
  u16* ab = (u16*)(Dreg + (size_t)3 * M * Dm * 2);
  u16* ffmid = (u16*)Dreg;                          // ffn: M x 4096

  dim3 blk(256);
  Src8 s8 = {{ (const float*)d_in[2], (const float*)d_in[4], (const float*)d_in[6],
               (const float*)d_in[8], (const float*)d_in[10], (const float*)d_in[12],
               (const float*)d_in[14], (const float*)d_in[16] }};
  transpose_cast8<<<dim3(32, 32, 8), blk, 0, stream>>>(s8, wt8);
  transpose_cast<<<dim3(Dm / 32, F / 32), blk, 0, stream>>>((const float*)d_in[18], ff1T, Dm, F);
  transpose_cast<<<dim3(F / 32, Dm / 32), blk, 0, stream>>>((const float*)d_in[20], ff2T, F, Dm);
  cast_f32_bf16<<<dim3((M * Dm / 4) / 256), blk, 0, stream>>>(enc, encb, M * Dm / 4);

  // 1-D XCD-swizzled GEMM grids (all divisible by 8)
  const int gproj = (M / 128) * (1024 / 128);   // 512
  const int gqkv  = (M / 128) * (3072 / 128);   // 1536
  const int gkv   = (M / 128) * (2048 / 128);   // 1024
  const int gffn1 = (M / 128) * (4096 / 128);   // 2048
  dim3 gattn((T / 128) * 64);

  // --- self-attention block ---
  ln_bf16<0><<<M, blk, 0, stream>>>(x, nullptr, (const float*)d_in[22], (const float*)d_in[23], h);
  gemm_bf16<4><<<gqkv, blk, 0, stream>>>(h, wt8,
      (const float*)d_in[3], (const float*)d_in[5], (const float*)d_in[7],
      nullptr, nullptr, qb, kb, vb, nullptr, M, 3072, Dm);
  attn_kernel<true><<<gattn, blk, 0, stream>>>(qb, kb, vb, ab, T, S);
  gemm_bf16<2><<<gproj, blk, 0, stream>>>(ab, wt8 + (size_t)3 * Dm * Dm,
      (const float*)d_in[9], nullptr, nullptr, x, nullptr, xc, nullptr, nullptr, nullptr, M, Dm, Dm);

  // --- cross-attention block ---
  ln_bf16<1><<<M, blk, 0, stream>>>(nullptr, xc, (const float*)d_in[24], (const float*)d_in[25], h);
  gemm_bf16<3><<<gproj, blk, 0, stream>>>(h, wt8 + (size_t)4 * Dm * Dm,
      (const float*)d_in[11], nullptr, nullptr, nullptr, nullptr, qb, nullptr, nullptr, nullptr, M, Dm, Dm);
  gemm_bf16<5><<<gkv, blk, 0, stream>>>(encb, wt8 + (size_t)5 * Dm * Dm,
      (const float*)d_in[13], (const float*)d_in[15], nullptr,
      nullptr, nullptr, kb, vb, nullptr, nullptr, M, 2048, Dm);
  attn_kernel<false><<<gattn, blk, 0, stream>>>(qb, kb, vb, ab, T, S);
  gemm_bf16<6><<<gproj, blk, 0, stream>>>(ab, wt8 + (size_t)7 * Dm * Dm,
      (const float*)d_in[17], nullptr, nullptr, nullptr, xc, xc2, nullptr, nullptr, nullptr, M, Dm, Dm);

  // --- FFN block ---
  ln_bf16<1><<<M, blk, 0, stream>>>(nullptr, xc2, (const float*)d_in[26], (const float*)d_in[27], h);
  gemm_bf16<1><<<gffn1, blk, 0, stream>>>(h, ff1T, (const float*)d_in[19],
      nullptr, nullptr, nullptr, nullptr, ffmid, nullptr, nullptr, nullptr, M, F, Dm);
  gemm_bf16<7><<<gproj, blk, 0, stream>>>(ffmid, ff2T, (const float*)d_in[21],
      nullptr, nullptr, nullptr, xc2, nullptr, nullptr, nullptr, (float*)d_out, M, Dm, F);
}

// Round 14
// 605.233 us; speedup vs baseline: 1.0974x; 1.0974x over previous
//
#include <hip/hip_runtime.h>
#include <stdint.h>

#define D_MODEL 1024
#define D_FF    4096
#define NHEADS  16
#define HD      64
#define LN_EPS  1e-5f

using u16 = unsigned short;
typedef __bf16 bf16x8 __attribute__((ext_vector_type(8)));
typedef float  f32x4  __attribute__((ext_vector_type(4)));
typedef float  f32x16 __attribute__((ext_vector_type(16)));

typedef __attribute__((address_space(1))) uint32_t as1_u32;
typedef __attribute__((address_space(3))) uint32_t as3_u32;

__device__ __forceinline__ u16 f2bf(float f) {
  union { float f; uint32_t u; } v; v.f = f;
  uint32_t r = v.u + 0x7FFFu + ((v.u >> 16) & 1u);
  return (u16)(r >> 16);
}

__device__ __forceinline__ float bf2f(u16 u) {
  union { uint32_t u; float f; } v; v.u = (uint32_t)u << 16; return v.f;
}

__device__ __forceinline__ uint32_t cvtpk(float lo, float hi) {
  uint32_t r;
  asm("v_cvt_pk_bf16_f32 %0, %1, %2" : "=v"(r) : "v"(lo), "v"(hi));
  return r;
}

__device__ __forceinline__ void gl_lds16(const void* g, void* l) {
  __builtin_amdgcn_global_load_lds((const as1_u32*)(uintptr_t)g,
                                   (as3_u32*)(uint32_t)(uintptr_t)l, 16, 0, 0);
}

// ---------------- transpose + cast: W (K x N, f32) -> Wt (N x K, bf16) ----------------
__global__ __launch_bounds__(256)
void transpose_cast(const float* __restrict__ W, u16* __restrict__ Wt, int K, int N) {
  __shared__ float t[32][33];
  const int k0 = blockIdx.x * 32, n0 = blockIdx.y * 32;
  const int x = threadIdx.x & 31, y = threadIdx.x >> 5;
#pragma unroll
  for (int j = 0; j < 32; j += 8)
    t[y + j][x] = W[(size_t)(k0 + y + j) * N + (n0 + x)];
  __syncthreads();
#pragma unroll
  for (int j = 0; j < 32; j += 8)
    Wt[(size_t)(n0 + y + j) * K + (k0 + x)] = f2bf(t[x][y + j]);
}

// 8 square (1024x1024) weight transposes in one dispatch; dst slabs contiguous.
struct Src8 { const float* s[8]; };
__global__ __launch_bounds__(256)
void transpose_cast8(Src8 p, u16* __restrict__ dstbase) {
  __shared__ float t[32][33];
  const float* __restrict__ W = p.s[blockIdx.z];
  u16* __restrict__ Wt = dstbase + (size_t)blockIdx.z * (1024 * 1024);
  const int k0 = blockIdx.x * 32, n0 = blockIdx.y * 32;
  const int x = threadIdx.x & 31, y = threadIdx.x >> 5;
#pragma unroll
  for (int j = 0; j < 32; j += 8)
    t[y + j][x] = W[(size_t)(k0 + y + j) * 1024 + (n0 + x)];
  __syncthreads();
#pragma unroll
  for (int j = 0; j < 32; j += 8)
    Wt[(size_t)(n0 + y + j) * 1024 + (k0 + x)] = f2bf(t[x][y + j]);
}

// ---------------- elementwise cast f32 -> bf16 ----------------
__global__ __launch_bounds__(256)
void cast_f32_bf16(const float* __restrict__ in, u16* __restrict__ out, int n4) {
  int i = blockIdx.x * 256 + threadIdx.x;
  if (i < n4) {
    float4 v = ((const float4*)in)[i];
    ushort4 o;
    o.x = f2bf(v.x); o.y = f2bf(v.y); o.z = f2bf(v.z); o.w = f2bf(v.w);
    ((ushort4*)out)[i] = o;
  }
}

// ---------------- LayerNorm (f32 or bf16 in, bf16 out), block per row ----------------
template<int BF16IN>
__global__ __launch_bounds__(256)
void ln_bf16(const float* __restrict__ xf, const u16* __restrict__ xb,
             const float* __restrict__ g, const float* __restrict__ bta,
             u16* __restrict__ out) {
  const int row = blockIdx.x;
  const int tid = threadIdx.x;
  float4 v;
  if (BF16IN) {
    ushort4 u = ((const ushort4*)(xb + (size_t)row * D_MODEL))[tid];
    v.x = bf2f(u.x); v.y = bf2f(u.y); v.z = bf2f(u.z); v.w = bf2f(u.w);
  } else {
    v = ((const float4*)(xf + (size_t)row * D_MODEL))[tid];
  }
  float s  = v.x + v.y + v.z + v.w;
  float s2 = v.x * v.x + v.y * v.y + v.z * v.z + v.w * v.w;
#pragma unroll
  for (int off = 1; off < 64; off <<= 1) {
    s  += __shfl_xor(s, off);
    s2 += __shfl_xor(s2, off);
  }
  __shared__ float sm[8];
  const int wave = tid >> 6, lane = tid & 63;
  if (lane == 0) { sm[wave] = s; sm[4 + wave] = s2; }
  __syncthreads();
  s  = sm[0] + sm[1] + sm[2] + sm[3];
  s2 = sm[4] + sm[5] + sm[6] + sm[7];
  const float mean = s * (1.f / D_MODEL);
  const float var  = s2 * (1.f / D_MODEL) - mean * mean;
  const float rstd = rsqrtf(var + LN_EPS);
  const float4 gv = ((const float4*)g)[tid];
  const float4 bv = ((const float4*)bta)[tid];
  ushort4 o;
  o.x = f2bf((v.x - mean) * rstd * gv.x + bv.x);
  o.y = f2bf((v.y - mean) * rstd * gv.y + bv.y);
  o.z = f2bf((v.z - mean) * rstd * gv.z + bv.z);
  o.w = f2bf((v.w - mean) * rstd * gv.w + bv.w);
  ((ushort4*)(out + (size_t)row * D_MODEL))[tid] = o;
}

// ---------------- GEMM: C[M,N] = A[M,K](bf16) * Wt[N,K]^T(bf16) + bias ----------------
// 2-D grid (r10-proven). EPI 0: bf16   EPI 1: relu->bf16
// EPI 2: bf16 = acc+bias+residf(f32)   EPI 3: bf16 * 0.125*log2e (Q proj)
// EPI 4: merged QKV -> 3 DENSE buffers, seg0 scaled
// EPI 5: merged KV  -> 2 DENSE buffers
// EPI 6: bf16 = acc+bias+residb(bf16)  EPI 7: f32 = acc+bias+residb(bf16)
#define QSCALE 0.18033688011112042f
template<int EPI>
__global__ __launch_bounds__(256, 3)
void gemm_bf16(const u16* __restrict__ A, const u16* __restrict__ Wt,
               const float* __restrict__ bias, const float* __restrict__ bias2,
               const float* __restrict__ bias3,
               const float* __restrict__ residf, const u16* __restrict__ residb,
               u16* __restrict__ outb, u16* __restrict__ outb2, u16* __restrict__ outb3,
               float* outf, int M, int N, int K) {
  __shared__ u16 lA[128 * 32];
  __shared__ u16 lB[128 * 32];
  const int tid  = threadIdx.x;
  const int lane = tid & 63;
  const int wave = tid >> 6;
  const int wr = wave >> 1, wc = wave & 1;
  const int lr = lane & 15, lg = lane >> 4;
  const int row0 = blockIdx.x * 128, col0 = blockIdx.y * 128;

  const char* pa = (const char*)A  + ((size_t)(row0 + (tid >> 2)) * K + (size_t)(tid & 3) * 8) * 2;
  const char* pb = (const char*)Wt + ((size_t)(col0 + (tid >> 2)) * K + (size_t)(tid & 3) * 8) * 2;
  const size_t rowskip = (size_t)64 * K * 2;
  char* la = (char*)lA + wave * 1024;
  char* lb = (char*)lB + wave * 1024;

  f32x4 acc[4][4] = {};
  const int ksteps = K >> 5;
  for (int kt = 0; kt < ksteps; ++kt) {
    gl_lds16(pa, la);
    gl_lds16(pa + rowskip, la + 4096);
    gl_lds16(pb, lb);
    gl_lds16(pb + rowskip, lb + 4096);
    pa += 64; pb += 64;
    __syncthreads();
    bf16x8 af[4], bfr[4];
#pragma unroll
    for (int m = 0; m < 4; ++m)
      af[m] = *(const bf16x8*)((const char*)lA + (wr * 64 + m * 16 + lr) * 64 + lg * 16);
#pragma unroll
    for (int n = 0; n < 4; ++n)
      bfr[n] = *(const bf16x8*)((const char*)lB + (wc * 64 + n * 16 + lr) * 64 + lg * 16);
#pragma unroll
    for (int m = 0; m < 4; ++m)
#pragma unroll
      for (int n = 0; n < 4; ++n)
        acc[m][n] = __builtin_amdgcn_mfma_f32_16x16x32_bf16(af[m], bfr[n], acc[m][n], 0, 0, 0);
    __syncthreads();
  }

#pragma unroll
  for (int m = 0; m < 4; ++m) {
    const int grow = row0 + wr * 64 + m * 16 + lg * 4;
#pragma unroll
    for (int n = 0; n < 4; ++n) {
      const int gcol = col0 + wc * 64 + n * 16 + lr;
      if (EPI == 4 || EPI == 5) {
        const int seg = gcol >> 10;
        const int c = gcol & 1023;
        float bv;
        float sc = 1.f;
        u16* optr;
        if (EPI == 4) {
          bv = ((seg == 0) ? bias : (seg == 1) ? bias2 : bias3)[c];
          optr = (seg == 0) ? outb : (seg == 1) ? outb2 : outb3;
          if (seg == 0) sc = QSCALE;
        } else {
          bv = (seg ? bias2 : bias)[c];
          optr = seg ? outb2 : outb;
        }
#pragma unroll
        for (int r = 0; r < 4; ++r)
          optr[(size_t)(grow + r) * 1024 + c] = f2bf((acc[m][n][r] + bv) * sc);
      } else {
        const float bv = bias[gcol];
#pragma unroll
        for (int r = 0; r < 4; ++r) {
          const size_t idx = (size_t)(grow + r) * N + gcol;
          float v = acc[m][n][r] + bv;
          if (EPI == 0)      outb[idx] = f2bf(v);
          else if (EPI == 1) outb[idx] = f2bf(v > 0.f ? v : 0.f);
          else if (EPI == 2) outb[idx] = f2bf(v + residf[idx]);
          else if (EPI == 3) outb[idx] = f2bf(v * QSCALE);
          else if (EPI == 6) outb[idx] = f2bf(v + bf2f(residb[idx]));
          else               outf[idx] = v + bf2f(residb[idx]);   // EPI 7
        }
      }
    }
  }
}

// ---------------- Flash attention, swapped-operand 32x32 form (r10-verified) ----------------
// 128 q-rows/block (4 waves x 32), 64-wide KV tiles. S^T = mfma(K,Q): lane owns
// one q-row (col=lane&31). K rows staged with sigma = swap bits 2<->3 so each
// lane OWNS the kv values its PV B-fragment needs (P = direct register packs).
// Dense V staged via reg roundtrip, swizzled by (d>>3)&7.
template<bool CAUSAL>
__global__ __launch_bounds__(256, 4)
void attn_kernel(const u16* __restrict__ Q, const u16* __restrict__ Kb,
                 const u16* __restrict__ Vb, u16* __restrict__ O,
                 int T, int S) {
  __shared__ u16 lQ[128 * 64];
  __shared__ u16 lK[64 * 64];
  __shared__ u16 lVt[64 * 64];

  const int f  = blockIdx.x;
  const int bh = f & 63;
  const int b = bh >> 4, hd = bh & 15;
  const int qx = f >> 6;
  const int q0 = (CAUSAL ? (T / 128 - 1 - qx) : qx) * 128;
  const int tid = threadIdx.x, lane = tid & 63, wave = tid >> 6;
  const int l31 = lane & 31, hb = lane >> 5;

  const u16* Qbase = Q  + (size_t)(b * T) * D_MODEL + hd * HD;
  const u16* Kbase = Kb + (size_t)(b * S) * D_MODEL + hd * HD;
  const u16* Vbase = Vb + (size_t)(b * S) * D_MODEL + hd * HD;
  const size_t rskip = (size_t)32 * D_MODEL * 2;

  const int srow = tid >> 3;
  const int sg   = (tid & 7) ^ (srow & 7);
  // sigma: swap bits 2<->3 (self-inverse). K source row only; bank-swizzle key
  // stays the physical dst row.
  const int sprow = (srow & ~12) | ((srow & 4) << 1) | ((srow & 8) >> 1);

  // stage Q: 128 rows x 128B (pre-swizzled source)
  {
    const char* src = (const char*)(Qbase + (size_t)(q0 + srow) * D_MODEL) + sg * 16;
    char* dst = (char*)lQ + wave * 1024;
    gl_lds16(src,             dst);
    gl_lds16(src + rskip,     dst + 4096);
    gl_lds16(src + 2 * rskip, dst + 8192);
    gl_lds16(src + 3 * rskip, dst + 12288);
  }

  bf16x8 qf[4];
  f32x16 oacc0 = {}, oacc1 = {};
  float m_run = -1e30f, l_run = 0.f;
  const int qq = q0 + wave * 32 + l31;   // this lane's q-row

  const int ktEnd = CAUSAL ? (q0 / 64 + 2) : (S / 64);

  for (int kt = 0; kt < ktEnd; ++kt) {
    // stage K tile: sigma-permuted source row, physical-row bank swizzle
    {
      const char* src = (const char*)(Kbase + (size_t)(kt * 64 + sprow) * D_MODEL) + sg * 16;
      char* dst = (char*)lK + wave * 1024;
      gl_lds16(src, dst);
      gl_lds16(src + rskip, dst + 4096);
    }
    // stage V^T (reg roundtrip), swizzled by (d>>3)&7
    {
      const u16* src = Vbase + (size_t)(kt * 64 + (tid >> 3)) * D_MODEL + (tid & 7) * 8;
      union { uint4 q; u16 s[8]; } v0, v1;
      v0.q = *(const uint4*)src;
      v1.q = *(const uint4*)(src + 32 * D_MODEL);
      const int key = tid >> 3, dbase = (tid & 7) * 8;
      const int kg0 = key >> 3, kb0 = (key & 7) * 2;
      const int kg1 = kg0 + 4;
#pragma unroll
      for (int j = 0; j < 8; ++j) {
        const int d = dbase + j;
        const int sw = (d >> 3) & 7;
        char* base = (char*)lVt + d * 128;
        *(u16*)(base + ((kg0 ^ sw) << 4) + kb0) = v0.s[j];
        *(u16*)(base + ((kg1 ^ sw) << 4) + kb0) = v1.s[j];
      }
    }
    __syncthreads();

    if (kt == 0) {
      const int qrow = wave * 32 + l31;
#pragma unroll
      for (int dc = 0; dc < 4; ++dc)
        qf[dc] = *(const bf16x8*)((const char*)lQ + qrow * 128 +
                                  (((2 * dc + hb) ^ (qrow & 7)) << 4));
    }

    const bool live = !CAUSAL || (kt * 64 <= q0 + wave * 32 + 31);
    if (live) {
      // QK^T swapped: S^T[sigma-permuted kv][q], two kv-halves of the 64-tile
      f32x16 z0 = {}, z1 = {};
      __builtin_amdgcn_s_setprio(1);
#pragma unroll
      for (int dc = 0; dc < 4; ++dc) {
        bf16x8 kf0 = *(const bf16x8*)((const char*)lK + l31 * 128 +
                                      (((2 * dc + hb) ^ (l31 & 7)) << 4));
        z0 = __builtin_amdgcn_mfma_f32_32x32x16_bf16(kf0, qf[dc], z0, 0, 0, 0);
      }
#pragma unroll
      for (int dc = 0; dc < 4; ++dc) {
        bf16x8 kf1 = *(const bf16x8*)((const char*)lK + (32 + l31) * 128 +
                                      (((2 * dc + hb) ^ (l31 & 7)) << 4));
        z1 = __builtin_amdgcn_mfma_f32_32x32x16_bf16(kf1, qf[dc], z1, 0, 0, 0);
      }
      __builtin_amdgcn_s_setprio(0);

      // causal mask: with sigma, reg r holds kv = kt*64 + (r&7) + 8*hb + 16*(r>>3)
      if (CAUSAL && kt * 64 + 63 > q0 + wave * 32) {
        const int kvb = kt * 64 + 8 * hb;
#pragma unroll
        for (int r = 0; r < 16; ++r) {
          const int kv = kvb + (r & 7) + 16 * (r >> 3);
          if (kv > qq)      z0[r] = -1e30f;
          if (kv + 32 > qq) z1[r] = -1e30f;
        }
      }

      // tree max (ILP-friendly) + cross-half shfl
      float t[16];
#pragma unroll
      for (int r = 0; r < 16; ++r) t[r] = fmaxf(z0[r], z1[r]);
#pragma unroll
      for (int sdt = 8; sdt >= 1; sdt >>= 1)
#pragma unroll
        for (int i = 0; i < 8; ++i)
          if (i < sdt) t[i] = fmaxf(t[i], t[i + sdt]);
      float mx = t[0];
      mx = fmaxf(mx, __shfl_xor(mx, 32));

      // defer-max rescale (THR = 8*log2e)
      if (!__all(mx - m_run <= 11.5f)) {
        const float mn = fmaxf(m_run, mx);
        const float scl = exp2f(m_run - mn);
        m_run = mn;
        l_run *= scl;
#pragma unroll
        for (int r = 0; r < 16; ++r) { oacc0[r] *= scl; oacc1[r] *= scl; }
      }
      float sum = 0.f;
#pragma unroll
      for (int r = 0; r < 16; ++r) {
        z0[r] = exp2f(z0[r] - m_run); sum += z0[r];
        z1[r] = exp2f(z1[r] - m_run); sum += z1[r];
      }
      sum += __shfl_xor(sum, 32);
      l_run += sum;

      // pack P to bf16 pairs; with sigma these ARE the PV B-fragments:
      // pf[c] = regs [8c..8c+7] (elem j -> kv = 16c + 8*hb + j)
      bf16x8 pf[4];
      {
        union { uint32_t u[4]; bf16x8 v; } w0, w1, w2, w3;
#pragma unroll
        for (int i = 0; i < 4; ++i) {
          w0.u[i] = cvtpk(z0[2 * i],     z0[2 * i + 1]);
          w1.u[i] = cvtpk(z0[8 + 2 * i], z0[9 + 2 * i]);
          w2.u[i] = cvtpk(z1[2 * i],     z1[2 * i + 1]);
          w3.u[i] = cvtpk(z1[8 + 2 * i], z1[9 + 2 * i]);
        }
        pf[0] = w0.v; pf[1] = w1.v; pf[2] = w2.v; pf[3] = w3.v;
      }

      // PV swapped: O^T[d][q] += V^T-frag x P^T-frag
      __builtin_amdgcn_s_setprio(1);
#pragma unroll
      for (int c = 0; c < 4; ++c) {
        bf16x8 vf0 = *(const bf16x8*)((const char*)lVt + l31 * 128 +
                       (((2 * c + hb) ^ ((l31 >> 3) & 7)) << 4));
        oacc0 = __builtin_amdgcn_mfma_f32_32x32x16_bf16(vf0, pf[c], oacc0, 0, 0, 0);
        bf16x8 vf1 = *(const bf16x8*)((const char*)lVt + (32 + l31) * 128 +
                       ((((2 * c + hb) ^ (((32 + l31) >> 3) & 7))) << 4));
        oacc1 = __builtin_amdgcn_mfma_f32_32x32x16_bf16(vf1, pf[c], oacc1, 0, 0, 0);
      }
      __builtin_amdgcn_s_setprio(0);
    }
    __syncthreads();
  }

  // epilogue: lane's column is its own q -> scalar l-division, packed 8B stores
  const float linv = 1.f / l_run;
  u16* Op = O + (size_t)(b * T + qq) * D_MODEL + hd * HD + 4 * hb;
#pragma unroll
  for (int rr = 0; rr < 4; ++rr) {
    uint2 st0, st1;
    st0.x = cvtpk(oacc0[4 * rr + 0] * linv, oacc0[4 * rr + 1] * linv);
    st0.y = cvtpk(oacc0[4 * rr + 2] * linv, oacc0[4 * rr + 3] * linv);
    *(uint2*)(Op + 8 * rr) = st0;
    st1.x = cvtpk(oacc1[4 * rr + 0] * linv, oacc1[4 * rr + 1] * linv);
    st1.y = cvtpk(oacc1[4 * rr + 2] * linv, oacc1[4 * rr + 3] * linv);
    *(uint2*)(Op + 32 + 8 * rr) = st1;
  }
}

// ---------------- host ----------------
extern "C" void kernel_launch(void* const* d_in, const int* in_sizes, int n_in,
                              void* d_out, int out_size, void* d_ws, size_t ws_size,
                              hipStream_t stream) {
  (void)in_sizes; (void)n_in; (void)out_size; (void)ws_size;
  const int B = 4, T = 2048, S = 2048, Dm = 1024, F = 4096;
  const int M = B * T;

  const float* x   = (const float*)d_in[0];
  const float* enc = (const float*)d_in[1];

  char* p = (char*)d_ws;
  auto take = [&](size_t bytes) { char* r = p; p += (bytes + 255) & ~(size_t)255; return r; };
  // [0]=sa_qw [1]=sa_kw [2]=sa_vw [3]=sa_ow [4]=ca_qw [5]=ca_kw [6]=ca_vw [7]=ca_ow
  u16* wt8  = (u16*)take((size_t)8 * Dm * Dm * 2);
  u16* ff1T = (u16*)take((size_t)F * Dm * 2);
  u16* ff2T = (u16*)take((size_t)Dm * F * 2);
  u16*   h    = (u16*)take((size_t)M * Dm * 2);
  u16*   encb = (u16*)take((size_t)M * Dm * 2);
  u16*   xc   = (u16*)take((size_t)M * Dm * 2);   // bf16 residual stream
  u16*   xc2  = (u16*)take((size_t)M * Dm * 2);
  char*  Dreg = take((size_t)M * F * 2);            // 64MB reusable region
  u16* qb = (u16*)Dreg;                             // M x 1024 dense
  u16* kb = (u16*)(Dreg + (size_t)M * Dm * 2);
  u16* vb = (u16*)(Dreg + (size_t)2 * M * Dm * 2);
  u16* ab = (u16*)(Dreg + (size_t)3 * M * Dm * 2);
  u16* ffmid = (u16*)Dreg;                          // ffn: M x 4096

  dim3 blk(256);
  Src8 s8 = {{ (const float*)d_in[2], (const float*)d_in[4], (const float*)d_in[6],
               (const float*)d_in[8], (const float*)d_in[10], (const float*)d_in[12],
               (const float*)d_in[14], (const float*)d_in[16] }};
  transpose_cast8<<<dim3(32, 32, 8), blk, 0, stream>>>(s8, wt8);
  transpose_cast<<<dim3(Dm / 32, F / 32), blk, 0, stream>>>((const float*)d_in[18], ff1T, Dm, F);
  transpose_cast<<<dim3(F / 32, Dm / 32), blk, 0, stream>>>((const float*)d_in[20], ff2T, F, Dm);
  cast_f32_bf16<<<dim3((M * Dm / 4) / 256), blk, 0, stream>>>(enc, encb, M * Dm / 4);

  dim3 gproj(M / 128, Dm / 128);
  dim3 gqkv(M / 128, 3072 / 128);
  dim3 gkv(M / 128, 2048 / 128);
  dim3 gffn1(M / 128, F / 128);
  dim3 gattn((T / 128) * 64);

  // --- self-attention block ---
  ln_bf16<0><<<M, blk, 0, stream>>>(x, nullptr, (const float*)d_in[22], (const float*)d_in[23], h);
  gemm_bf16<4><<<gqkv, blk, 0, stream>>>(h, wt8,
      (const float*)d_in[3], (const float*)d_in[5], (const float*)d_in[7],
      nullptr, nullptr, qb, kb, vb, nullptr, M, 3072, Dm);
  attn_kernel<true><<<gattn, blk, 0, stream>>>(qb, kb, vb, ab, T, S);
  gemm_bf16<2><<<gproj, blk, 0, stream>>>(ab, wt8 + (size_t)3 * Dm * Dm,
      (const float*)d_in[9], nullptr, nullptr, x, nullptr, xc, nullptr, nullptr, nullptr, M, Dm, Dm);

  // --- cross-attention block ---
  ln_bf16<1><<<M, blk, 0, stream>>>(nullptr, xc, (const float*)d_in[24], (const float*)d_in[25], h);
  gemm_bf16<3><<<gproj, blk, 0, stream>>>(h, wt8 + (size_t)4 * Dm * Dm,
      (const float*)d_in[11], nullptr, nullptr, nullptr, nullptr, qb, nullptr, nullptr, nullptr, M, Dm, Dm);
  gemm_bf16<5><<<gkv, blk, 0, stream>>>(encb, wt8 + (size_t)5 * Dm * Dm,
      (const float*)d_in[13], (const float*)d_in[15], nullptr,
      nullptr, nullptr, kb, vb, nullptr, nullptr, M, 2048, Dm);
  attn_kernel<false><<<gattn, blk, 0, stream>>>(qb, kb, vb, ab, T, S);
  gemm_bf16<6><<<gproj, blk, 0, stream>>>(ab, wt8 + (size_t)7 * Dm * Dm,
      (const float*)d_in[17], nullptr, nullptr, nullptr, xc, xc2, nullptr, nullptr, nullptr, M, Dm, Dm);

  // --- FFN block ---
  ln_bf16<1><<<M, blk, 0, stream>>>(nullptr, xc2, (const float*)d_in[26], (const float*)d_in[27], h);
  gemm_bf16<1><<<gffn1, blk, 0, stream>>>(h, ff1T, (const float*)d_in[19],
      nullptr, nullptr, nullptr, nullptr, ffmid, nullptr, nullptr, nullptr, M, F, Dm);
  gemm_bf16<7><<<gproj, blk, 0, stream>>>(ffmid, ff2T, (const float*)d_in[21],
      nullptr, nullptr, nullptr, xc2, nullptr, nullptr, nullptr, (float*)d_out, M, Dm, F);
}

// Round 15
// 562.554 us; speedup vs baseline: 1.1807x; 1.0759x over previous
//
#include <hip/hip_runtime.h>
#include <stdint.h>

#define D_MODEL 1024
#define D_FF    4096
#define NHEADS  16
#define HD      64
#define LN_EPS  1e-5f

using u16 = unsigned short;
typedef __bf16 bf16x8 __attribute__((ext_vector_type(8)));
typedef float  f32x4  __attribute__((ext_vector_type(4)));
typedef float  f32x16 __attribute__((ext_vector_type(16)));

typedef __attribute__((address_space(1))) uint32_t as1_u32;
typedef __attribute__((address_space(3))) uint32_t as3_u32;

__device__ __forceinline__ u16 f2bf(float f) {
  union { float f; uint32_t u; } v; v.f = f;
  uint32_t r = v.u + 0x7FFFu + ((v.u >> 16) & 1u);
  return (u16)(r >> 16);
}

__device__ __forceinline__ float bf2f(u16 u) {
  union { uint32_t u; float f; } v; v.u = (uint32_t)u << 16; return v.f;
}

__device__ __forceinline__ uint32_t cvtpk(float lo, float hi) {
  uint32_t r;
  asm("v_cvt_pk_bf16_f32 %0, %1, %2" : "=v"(r) : "v"(lo), "v"(hi));
  return r;
}

__device__ __forceinline__ void gl_lds16(const void* g, void* l) {
  __builtin_amdgcn_global_load_lds((const as1_u32*)(uintptr_t)g,
                                   (as3_u32*)(uint32_t)(uintptr_t)l, 16, 0, 0);
}

// ---------------- transpose + cast: W (K x N, f32) -> Wt (N x K, bf16) ----------------
__global__ __launch_bounds__(256)
void transpose_cast(const float* __restrict__ W, u16* __restrict__ Wt, int K, int N) {
  __shared__ float t[32][33];
  const int k0 = blockIdx.x * 32, n0 = blockIdx.y * 32;
  const int x = threadIdx.x & 31, y = threadIdx.x >> 5;
#pragma unroll
  for (int j = 0; j < 32; j += 8)
    t[y + j][x] = W[(size_t)(k0 + y + j) * N + (n0 + x)];
  __syncthreads();
#pragma unroll
  for (int j = 0; j < 32; j += 8)
    Wt[(size_t)(n0 + y + j) * K + (k0 + x)] = f2bf(t[x][y + j]);
}

// 8 square (1024x1024) weight transposes in one dispatch; dst slabs contiguous.
struct Src8 { const float* s[8]; };
__global__ __launch_bounds__(256)
void transpose_cast8(Src8 p, u16* __restrict__ dstbase) {
  __shared__ float t[32][33];
  const float* __restrict__ W = p.s[blockIdx.z];
  u16* __restrict__ Wt = dstbase + (size_t)blockIdx.z * (1024 * 1024);
  const int k0 = blockIdx.x * 32, n0 = blockIdx.y * 32;
  const int x = threadIdx.x & 31, y = threadIdx.x >> 5;
#pragma unroll
  for (int j = 0; j < 32; j += 8)
    t[y + j][x] = W[(size_t)(k0 + y + j) * 1024 + (n0 + x)];
  __syncthreads();
#pragma unroll
  for (int j = 0; j < 32; j += 8)
    Wt[(size_t)(n0 + y + j) * 1024 + (k0 + x)] = f2bf(t[x][y + j]);
}

// ---------------- elementwise cast f32 -> bf16 ----------------
__global__ __launch_bounds__(256)
void cast_f32_bf16(const float* __restrict__ in, u16* __restrict__ out, int n4) {
  int i = blockIdx.x * 256 + threadIdx.x;
  if (i < n4) {
    float4 v = ((const float4*)in)[i];
    ushort4 o;
    o.x = f2bf(v.x); o.y = f2bf(v.y); o.z = f2bf(v.z); o.w = f2bf(v.w);
    ((ushort4*)out)[i] = o;
  }
}

// ---------------- LayerNorm (f32 or bf16 in, bf16 out), block per row ----------------
template<int BF16IN>
__global__ __launch_bounds__(256)
void ln_bf16(const float* __restrict__ xf, const u16* __restrict__ xb,
             const float* __restrict__ g, const float* __restrict__ bta,
             u16* __restrict__ out) {
  const int row = blockIdx.x;
  const int tid = threadIdx.x;
  float4 v;
  if (BF16IN) {
    ushort4 u = ((const ushort4*)(xb + (size_t)row * D_MODEL))[tid];
    v.x = bf2f(u.x); v.y = bf2f(u.y); v.z = bf2f(u.z); v.w = bf2f(u.w);
  } else {
    v = ((const float4*)(xf + (size_t)row * D_MODEL))[tid];
  }
  float s  = v.x + v.y + v.z + v.w;
  float s2 = v.x * v.x + v.y * v.y + v.z * v.z + v.w * v.w;
#pragma unroll
  for (int off = 1; off < 64; off <<= 1) {
    s  += __shfl_xor(s, off);
    s2 += __shfl_xor(s2, off);
  }
  __shared__ float sm[8];
  const int wave = tid >> 6, lane = tid & 63;
  if (lane == 0) { sm[wave] = s; sm[4 + wave] = s2; }
  __syncthreads();
  s  = sm[0] + sm[1] + sm[2] + sm[3];
  s2 = sm[4] + sm[5] + sm[6] + sm[7];
  const float mean = s * (1.f / D_MODEL);
  const float var  = s2 * (1.f / D_MODEL) - mean * mean;
  const float rstd = rsqrtf(var + LN_EPS);
  const float4 gv = ((const float4*)g)[tid];
  const float4 bv = ((const float4*)bta)[tid];
  ushort4 o;
  o.x = f2bf((v.x - mean) * rstd * gv.x + bv.x);
  o.y = f2bf((v.y - mean) * rstd * gv.y + bv.y);
  o.z = f2bf((v.z - mean) * rstd * gv.z + bv.z);
  o.w = f2bf((v.w - mean) * rstd * gv.w + bv.w);
  ((ushort4*)(out + (size_t)row * D_MODEL))[tid] = o;
}

// ---------------- GEMM: C[M,N] = A[M,K](bf16) * Wt[N,K]^T(bf16) + bias ----------------
// BK=64 K-step (half the barrier drains of BK=32); LDS [128][64] bf16 with the
// attn-proven XOR swizzle: slot (row, g) holds global granule g^(row&7) via
// pre-swizzled source; reads XOR the same key so the net K-permutation cancels.
// 2-D grid. EPI 0: bf16   EPI 1: relu->bf16
// EPI 2: bf16 = acc+bias+residf(f32)   EPI 3: bf16 * 0.125*log2e (Q proj)
// EPI 4: merged QKV -> 3 DENSE buffers, seg0 scaled
// EPI 5: merged KV  -> 2 DENSE buffers
// EPI 6: bf16 = acc+bias+residb(bf16)  EPI 7: f32 = acc+bias+residb(bf16)
#define QSCALE 0.18033688011112042f
template<int EPI>
__global__ __launch_bounds__(256, 3)
void gemm_bf16(const u16* __restrict__ A, const u16* __restrict__ Wt,
               const float* __restrict__ bias, const float* __restrict__ bias2,
               const float* __restrict__ bias3,
               const float* __restrict__ residf, const u16* __restrict__ residb,
               u16* __restrict__ outb, u16* __restrict__ outb2, u16* __restrict__ outb3,
               float* outf, int M, int N, int K) {
  __shared__ u16 lA[128 * 64];
  __shared__ u16 lB[128 * 64];
  const int tid  = threadIdx.x;
  const int lane = tid & 63;
  const int wave = tid >> 6;
  const int wr = wave >> 1, wc = wave & 1;
  const int lr = lane & 15, lg = lane >> 4;
  const int row0 = blockIdx.x * 128, col0 = blockIdx.y * 128;

  // staging: thread covers LDS slot (row = tid>>3, granule = tid&7) of each
  // 32-row chunk; source granule pre-swizzled by row&7 (invariant across chunks)
  const int srow8 = tid >> 3;
  const int sg    = (tid & 7) ^ (srow8 & 7);
  const char* pa = (const char*)A  + ((size_t)(row0 + srow8) * K) * 2 + sg * 16;
  const char* pb = (const char*)Wt + ((size_t)(col0 + srow8) * K) * 2 + sg * 16;
  const size_t cskip = (size_t)32 * K * 2;
  char* la = (char*)lA + wave * 1024;
  char* lb = (char*)lB + wave * 1024;

  f32x4 acc[4][4] = {};
  const int ksteps = K >> 6;
  for (int kt = 0; kt < ksteps; ++kt) {
    gl_lds16(pa,             la);
    gl_lds16(pa + cskip,     la + 4096);
    gl_lds16(pa + 2 * cskip, la + 8192);
    gl_lds16(pa + 3 * cskip, la + 12288);
    gl_lds16(pb,             lb);
    gl_lds16(pb + cskip,     lb + 4096);
    gl_lds16(pb + 2 * cskip, lb + 8192);
    gl_lds16(pb + 3 * cskip, lb + 12288);
    pa += 128; pb += 128;
    __syncthreads();
#pragma unroll
    for (int kk = 0; kk < 2; ++kk) {
      bf16x8 af[4], bfr[4];
#pragma unroll
      for (int m = 0; m < 4; ++m) {
        const int rr = wr * 64 + m * 16 + lr;
        af[m] = *(const bf16x8*)((const char*)lA + rr * 128 +
                                 (((kk * 4 + lg) ^ (rr & 7)) << 4));
      }
#pragma unroll
      for (int n = 0; n < 4; ++n) {
        const int rr = wc * 64 + n * 16 + lr;
        bfr[n] = *(const bf16x8*)((const char*)lB + rr * 128 +
                                  (((kk * 4 + lg) ^ (rr & 7)) << 4));
      }
#pragma unroll
      for (int m = 0; m < 4; ++m)
#pragma unroll
        for (int n = 0; n < 4; ++n)
          acc[m][n] = __builtin_amdgcn_mfma_f32_16x16x32_bf16(af[m], bfr[n], acc[m][n], 0, 0, 0);
    }
    __syncthreads();
  }

#pragma unroll
  for (int m = 0; m < 4; ++m) {
    const int grow = row0 + wr * 64 + m * 16 + lg * 4;
#pragma unroll
    for (int n = 0; n < 4; ++n) {
      const int gcol = col0 + wc * 64 + n * 16 + lr;
      if (EPI == 4 || EPI == 5) {
        const int seg = gcol >> 10;
        const int c = gcol & 1023;
        float bv;
        float sc = 1.f;
        u16* optr;
        if (EPI == 4) {
          bv = ((seg == 0) ? bias : (seg == 1) ? bias2 : bias3)[c];
          optr = (seg == 0) ? outb : (seg == 1) ? outb2 : outb3;
          if (seg == 0) sc = QSCALE;
        } else {
          bv = (seg ? bias2 : bias)[c];
          optr = seg ? outb2 : outb;
        }
#pragma unroll
        for (int r = 0; r < 4; ++r)
          optr[(size_t)(grow + r) * 1024 + c] = f2bf((acc[m][n][r] + bv) * sc);
      } else {
        const float bv = bias[gcol];
#pragma unroll
        for (int r = 0; r < 4; ++r) {
          const size_t idx = (size_t)(grow + r) * N + gcol;
          float v = acc[m][n][r] + bv;
          if (EPI == 0)      outb[idx] = f2bf(v);
          else if (EPI == 1) outb[idx] = f2bf(v > 0.f ? v : 0.f);
          else if (EPI == 2) outb[idx] = f2bf(v + residf[idx]);
          else if (EPI == 3) outb[idx] = f2bf(v * QSCALE);
          else if (EPI == 6) outb[idx] = f2bf(v + bf2f(residb[idx]));
          else               outf[idx] = v + bf2f(residb[idx]);   // EPI 7
        }
      }
    }
  }
}

// ---------------- Flash attention, swapped-operand 32x32 form (r10-verified) ----------------
// 128 q-rows/block (4 waves x 32), 64-wide KV tiles. S^T = mfma(K,Q): lane owns
// one q-row (col=lane&31). K rows staged with sigma = swap bits 2<->3 so each
// lane OWNS the kv values its PV B-fragment needs (P = direct register packs).
// Dense V staged via reg roundtrip, swizzled by (d>>3)&7.
template<bool CAUSAL>
__global__ __launch_bounds__(256, 4)
void attn_kernel(const u16* __restrict__ Q, const u16* __restrict__ Kb,
                 const u16* __restrict__ Vb, u16* __restrict__ O,
                 int T, int S) {
  __shared__ u16 lQ[128 * 64];
  __shared__ u16 lK[64 * 64];
  __shared__ u16 lVt[64 * 64];

  const int f  = blockIdx.x;
  const int bh = f & 63;
  const int b = bh >> 4, hd = bh & 15;
  const int qx = f >> 6;
  const int q0 = (CAUSAL ? (T / 128 - 1 - qx) : qx) * 128;
  const int tid = threadIdx.x, lane = tid & 63, wave = tid >> 6;
  const int l31 = lane & 31, hb = lane >> 5;

  const u16* Qbase = Q  + (size_t)(b * T) * D_MODEL + hd * HD;
  const u16* Kbase = Kb + (size_t)(b * S) * D_MODEL + hd * HD;
  const u16* Vbase = Vb + (size_t)(b * S) * D_MODEL + hd * HD;
  const size_t rskip = (size_t)32 * D_MODEL * 2;

  const int srow = tid >> 3;
  const int sg   = (tid & 7) ^ (srow & 7);
  // sigma: swap bits 2<->3 (self-inverse). K source row only; bank-swizzle key
  // stays the physical dst row.
  const int sprow = (srow & ~12) | ((srow & 4) << 1) | ((srow & 8) >> 1);

  // stage Q: 128 rows x 128B (pre-swizzled source)
  {
    const char* src = (const char*)(Qbase + (size_t)(q0 + srow) * D_MODEL) + sg * 16;
    char* dst = (char*)lQ + wave * 1024;
    gl_lds16(src,             dst);
    gl_lds16(src + rskip,     dst + 4096);
    gl_lds16(src + 2 * rskip, dst + 8192);
    gl_lds16(src + 3 * rskip, dst + 12288);
  }

  bf16x8 qf[4];
  f32x16 oacc0 = {}, oacc1 = {};
  float m_run = -1e30f, l_run = 0.f;
  const int qq = q0 + wave * 32 + l31;   // this lane's q-row

  const int ktEnd = CAUSAL ? (q0 / 64 + 2) : (S / 64);

  for (int kt = 0; kt < ktEnd; ++kt) {
    // stage K tile: sigma-permuted source row, physical-row bank swizzle
    {
      const char* src = (const char*)(Kbase + (size_t)(kt * 64 + sprow) * D_MODEL) + sg * 16;
      char* dst = (char*)lK + wave * 1024;
      gl_lds16(src, dst);
      gl_lds16(src + rskip, dst + 4096);
    }
    // stage V^T (reg roundtrip), swizzled by (d>>3)&7
    {
      const u16* src = Vbase + (size_t)(kt * 64 + (tid >> 3)) * D_MODEL + (tid & 7) * 8;
      union { uint4 q; u16 s[8]; } v0, v1;
      v0.q = *(const uint4*)src;
      v1.q = *(const uint4*)(src + 32 * D_MODEL);
      const int key = tid >> 3, dbase = (tid & 7) * 8;
      const int kg0 = key >> 3, kb0 = (key & 7) * 2;
      const int kg1 = kg0 + 4;
#pragma unroll
      for (int j = 0; j < 8; ++j) {
        const int d = dbase + j;
        const int sw = (d >> 3) & 7;
        char* base = (char*)lVt + d * 128;
        *(u16*)(base + ((kg0 ^ sw) << 4) + kb0) = v0.s[j];
        *(u16*)(base + ((kg1 ^ sw) << 4) + kb0) = v1.s[j];
      }
    }
    __syncthreads();

    if (kt == 0) {
      const int qrow = wave * 32 + l31;
#pragma unroll
      for (int dc = 0; dc < 4; ++dc)
        qf[dc] = *(const bf16x8*)((const char*)lQ + qrow * 128 +
                                  (((2 * dc + hb) ^ (qrow & 7)) << 4));
    }

    const bool live = !CAUSAL || (kt * 64 <= q0 + wave * 32 + 31);
    if (live) {
      // QK^T swapped: S^T[sigma-permuted kv][q], two kv-halves of the 64-tile
      f32x16 z0 = {}, z1 = {};
      __builtin_amdgcn_s_setprio(1);
#pragma unroll
      for (int dc = 0; dc < 4; ++dc) {
        bf16x8 kf0 = *(const bf16x8*)((const char*)lK + l31 * 128 +
                                      (((2 * dc + hb) ^ (l31 & 7)) << 4));
        z0 = __builtin_amdgcn_mfma_f32_32x32x16_bf16(kf0, qf[dc], z0, 0, 0, 0);
      }
#pragma unroll
      for (int dc = 0; dc < 4; ++dc) {
        bf16x8 kf1 = *(const bf16x8*)((const char*)lK + (32 + l31) * 128 +
                                      (((2 * dc + hb) ^ (l31 & 7)) << 4));
        z1 = __builtin_amdgcn_mfma_f32_32x32x16_bf16(kf1, qf[dc], z1, 0, 0, 0);
      }
      __builtin_amdgcn_s_setprio(0);

      // causal mask: with sigma, reg r holds kv = kt*64 + (r&7) + 8*hb + 16*(r>>3)
      if (CAUSAL && kt * 64 + 63 > q0 + wave * 32) {
        const int kvb = kt * 64 + 8 * hb;
#pragma unroll
        for (int r = 0; r < 16; ++r) {
          const int kv = kvb + (r & 7) + 16 * (r >> 3);
          if (kv > qq)      z0[r] = -1e30f;
          if (kv + 32 > qq) z1[r] = -1e30f;
        }
      }

      // tree max (ILP-friendly) + cross-half shfl
      float t[16];
#pragma unroll
      for (int r = 0; r < 16; ++r) t[r] = fmaxf(z0[r], z1[r]);
#pragma unroll
      for (int sdt = 8; sdt >= 1; sdt >>= 1)
#pragma unroll
        for (int i = 0; i < 8; ++i)
          if (i < sdt) t[i] = fmaxf(t[i], t[i + sdt]);
      float mx = t[0];
      mx = fmaxf(mx, __shfl_xor(mx, 32));

      // defer-max rescale (THR = 8*log2e)
      if (!__all(mx - m_run <= 11.5f)) {
        const float mn = fmaxf(m_run, mx);
        const float scl = exp2f(m_run - mn);
        m_run = mn;
        l_run *= scl;
#pragma unroll
        for (int r = 0; r < 16; ++r) { oacc0[r] *= scl; oacc1[r] *= scl; }
      }
      float sum = 0.f;
#pragma unroll
      for (int r = 0; r < 16; ++r) {
        z0[r] = exp2f(z0[r] - m_run); sum += z0[r];
        z1[r] = exp2f(z1[r] - m_run); sum += z1[r];
      }
      sum += __shfl_xor(sum, 32);
      l_run += sum;

      // pack P to bf16 pairs; with sigma these ARE the PV B-fragments:
      // pf[c] = regs [8c..8c+7] (elem j -> kv = 16c + 8*hb + j)
      bf16x8 pf[4];
      {
        union { uint32_t u[4]; bf16x8 v; } w0, w1, w2, w3;
#pragma unroll
        for (int i = 0; i < 4; ++i) {
          w0.u[i] = cvtpk(z0[2 * i],     z0[2 * i + 1]);
          w1.u[i] = cvtpk(z0[8 + 2 * i], z0[9 + 2 * i]);
          w2.u[i] = cvtpk(z1[2 * i],     z1[2 * i + 1]);
          w3.u[i] = cvtpk(z1[8 + 2 * i], z1[9 + 2 * i]);
        }
        pf[0] = w0.v; pf[1] = w1.v; pf[2] = w2.v; pf[3] = w3.v;
      }

      // PV swapped: O^T[d][q] += V^T-frag x P^T-frag
      __builtin_amdgcn_s_setprio(1);
#pragma unroll
      for (int c = 0; c < 4; ++c) {
        bf16x8 vf0 = *(const bf16x8*)((const char*)lVt + l31 * 128 +
                       (((2 * c + hb) ^ ((l31 >> 3) & 7)) << 4));
        oacc0 = __builtin_amdgcn_mfma_f32_32x32x16_bf16(vf0, pf[c], oacc0, 0, 0, 0);
        bf16x8 vf1 = *(const bf16x8*)((const char*)lVt + (32 + l31) * 128 +
                       ((((2 * c + hb) ^ (((32 + l31) >> 3) & 7))) << 4));
        oacc1 = __builtin_amdgcn_mfma_f32_32x32x16_bf16(vf1, pf[c], oacc1, 0, 0, 0);
      }
      __builtin_amdgcn_s_setprio(0);
    }
    __syncthreads();
  }

  // epilogue: lane's column is its own q -> scalar l-division, packed 8B stores
  const float linv = 1.f / l_run;
  u16* Op = O + (size_t)(b * T + qq) * D_MODEL + hd * HD + 4 * hb;
#pragma unroll
  for (int rr = 0; rr < 4; ++rr) {
    uint2 st0, st1;
    st0.x = cvtpk(oacc0[4 * rr + 0] * linv, oacc0[4 * rr + 1] * linv);
    st0.y = cvtpk(oacc0[4 * rr + 2] * linv, oacc0[4 * rr + 3] * linv);
    *(uint2*)(Op + 8 * rr) = st0;
    st1.x = cvtpk(oacc1[4 * rr + 0] * linv, oacc1[4 * rr + 1] * linv);
    st1.y = cvtpk(oacc1[4 * rr + 2] * linv, oacc1[4 * rr + 3] * linv);
    *(uint2*)(Op + 32 + 8 * rr) = st1;
  }
}

// ---------------- host ----------------
extern "C" void kernel_launch(void* const* d_in, const int* in_sizes, int n_in,
                              void* d_out, int out_size, void* d_ws, size_t ws_size,
                              hipStream_t stream) {
  (void)in_sizes; (void)n_in; (void)out_size; (void)ws_size;
  const int B = 4, T = 2048, S = 2048, Dm = 1024, F = 4096;
  const int M = B * T;

  const float* x   = (const float*)d_in[0];
  const float* enc = (const float*)d_in[1];

  char* p = (char*)d_ws;
  auto take = [&](size_t bytes) { char* r = p; p += (bytes + 255) & ~(size_t)255; return r; };
  // [0]=sa_qw [1]=sa_kw [2]=sa_vw [3]=sa_ow [4]=ca_qw [5]=ca_kw [6]=ca_vw [7]=ca_ow
  u16* wt8  = (u16*)take((size_t)8 * Dm * Dm * 2);
  u16* ff1T = (u16*)take((size_t)F * Dm * 2);
  u16* ff2T = (u16*)take((size_t)Dm * F * 2);
  u16*   h    = (u16*)take((size_t)M * Dm * 2);
  u16*   encb = (u16*)take((size_t)M * Dm * 2);
  u16*   xc   = (u16*)take((size_t)M * Dm * 2);   // bf16 residual stream
  u16*   xc2  = (u16*)take((size_t)M * Dm * 2);
  char*  Dreg = take((size_t)M * F * 2);            // 64MB reusable region
  u16* qb = (u16*)Dreg;                             // M x 1024 dense
  u16* kb = (u16*)(Dreg + (size_t)M * Dm * 2);
  u16* vb = (u16*)(Dreg + (size_t)2 * M * Dm * 2);
  u16* ab = (u16*)(Dreg + (size_t)3 * M * Dm * 2);
  u16* ffmid = (u16*)Dreg;                          // ffn: M x 4096

  dim3 blk(256);
  Src8 s8 = {{ (const float*)d_in[2], (const float*)d_in[4], (const float*)d_in[6],
               (const float*)d_in[8], (const float*)d_in[10], (const float*)d_in[12],
               (const float*)d_in[14], (const float*)d_in[16] }};
  transpose_cast8<<<dim3(32, 32, 8), blk, 0, stream>>>(s8, wt8);
  transpose_cast<<<dim3(Dm / 32, F / 32), blk, 0, stream>>>((const float*)d_in[18], ff1T, Dm, F);
  transpose_cast<<<dim3(F / 32, Dm / 32), blk, 0, stream>>>((const float*)d_in[20], ff2T, F, Dm);
  cast_f32_bf16<<<dim3((M * Dm / 4) / 256), blk, 0, stream>>>(enc, encb, M * Dm / 4);

  dim3 gproj(M / 128, Dm / 128);
  dim3 gqkv(M / 128, 3072 / 128);
  dim3 gkv(M / 128, 2048 / 128);
  dim3 gffn1(M / 128, F / 128);
  dim3 gattn((T / 128) * 64);

  // --- self-attention block ---
  ln_bf16<0><<<M, blk, 0, stream>>>(x, nullptr, (const float*)d_in[22], (const float*)d_in[23], h);
  gemm_bf16<4><<<gqkv, blk, 0, stream>>>(h, wt8,
      (const float*)d_in[3], (const float*)d_in[5], (const float*)d_in[7],
      nullptr, nullptr, qb, kb, vb, nullptr, M, 3072, Dm);
  attn_kernel<true><<<gattn, blk, 0, stream>>>(qb, kb, vb, ab, T, S);
  gemm_bf16<2><<<gproj, blk, 0, stream>>>(ab, wt8 + (size_t)3 * Dm * Dm,
      (const float*)d_in[9], nullptr, nullptr, x, nullptr, xc, nullptr, nullptr, nullptr, M, Dm, Dm);

  // --- cross-attention block ---
  ln_bf16<1><<<M, blk, 0, stream>>>(nullptr, xc, (const float*)d_in[24], (const float*)d_in[25], h);
  gemm_bf16<3><<<gproj, blk, 0, stream>>>(h, wt8 + (size_t)4 * Dm * Dm,
      (const float*)d_in[11], nullptr, nullptr, nullptr, nullptr, qb, nullptr, nullptr, nullptr, M, Dm, Dm);
  gemm_bf16<5><<<gkv, blk, 0, stream>>>(encb, wt8 + (size_t)5 * Dm * Dm,
      (const float*)d_in[13], (const float*)d_in[15], nullptr,
      nullptr, nullptr, kb, vb, nullptr, nullptr, M, 2048, Dm);
  attn_kernel<false><<<gattn, blk, 0, stream>>>(qb, kb, vb, ab, T, S);
  gemm_bf16<6><<<gproj, blk, 0, stream>>>(ab, wt8 + (size_t)7 * Dm * Dm,
      (const float*)d_in[17], nullptr, nullptr, nullptr, xc, xc2, nullptr, nullptr, nullptr, M, Dm, Dm);

  // --- FFN block ---
  ln_bf16<1><<<M, blk, 0, stream>>>(nullptr, xc2, (const float*)d_in[26], (const float*)d_in[27], h);
  gemm_bf16<1><<<gffn1, blk, 0, stream>>>(h, ff1T, (const float*)d_in[19],
      nullptr, nullptr, nullptr, nullptr, ffmid, nullptr, nullptr, nullptr, M, F, Dm);
  gemm_bf16<7><<<gproj, blk, 0, stream>>>(ffmid, ff2T, (const float*)d_in[21],
      nullptr, nullptr, nullptr, xc2, nullptr, nullptr, nullptr, (float*)d_out, M, Dm, F);
}